// Round 8
// baseline (623.457 us; speedup 1.0000x reference)
//
#include <hip/hip_runtime.h>
#include <hip/hip_fp16.h>

#define N_NODES 50000
#define N_EDGES 800000

typedef _Float16 h8 __attribute__((ext_vector_type(8)));
typedef float f4 __attribute__((ext_vector_type(4)));

__device__ __forceinline__ float lrelu(float x){ return x > 0.f ? x : 0.2f*x; }
__device__ __forceinline__ float eluf (float x){ return x > 0.f ? x : __expf(x)-1.f; }

// ---------------- CSR build (+ fused weight transpose) ----------------
__global__ void k_histwt(const int* __restrict__ dst, int* __restrict__ cnt,
                         const float* __restrict__ W1, const float* __restrict__ W2,
                         const float* __restrict__ W3, const float* __restrict__ W4,
                         _Float16* __restrict__ wt){
  int b = blockIdx.x;
  if (b < 3125){
    int e = b*256 + threadIdx.x;
    if (e < N_EDGES) atomicAdd(&cnt[dst[e]], 1);
  } else {
    int id = (b - 3125)*256 + threadIdx.x;     // 81920 total wt elements
    if (id < 81920){
      const float* W; int HF; int loc;
      if (id < 16384)      { W = W1; HF = 128; loc = id; }
      else if (id < 32768) { W = W2; HF = 128; loc = id - 16384; }
      else if (id < 49152) { W = W3; HF = 128; loc = id - 32768; }
      else                 { W = W4; HF = 256; loc = id - 49152; }
      int n = loc >> 7, k = loc & 127;
      wt[id] = (_Float16)W[(size_t)k*HF + n];
    }
  }
}

__global__ void k_scan1(const int* __restrict__ cnt, int* __restrict__ offs, int* __restrict__ bsum){
  __shared__ int tmp[256];
  int tid = threadIdx.x; int i = blockIdx.x*256 + tid;
  int v = (i < N_NODES) ? cnt[i] : 0;
  tmp[tid] = v; __syncthreads();
  for (int d = 1; d < 256; d <<= 1){
    int t = (tid >= d) ? tmp[tid-d] : 0;
    __syncthreads();
    tmp[tid] += t;
    __syncthreads();
  }
  if (i < N_NODES) offs[i] = tmp[tid] - v;
  if (tid == 255) bsum[blockIdx.x] = tmp[tid];
}

__global__ void k_scan2(int* __restrict__ bsum, int nb){
  __shared__ int tmp[256];
  int tid = threadIdx.x;
  int v = (tid < nb) ? bsum[tid] : 0;
  tmp[tid] = v; __syncthreads();
  for (int d = 1; d < 256; d <<= 1){
    int t = (tid >= d) ? tmp[tid-d] : 0;
    __syncthreads();
    tmp[tid] += t;
    __syncthreads();
  }
  if (tid < nb) bsum[tid] = tmp[tid] - v;
}

__global__ void k_scan3(int* __restrict__ offs, const int* __restrict__ bsum, int* __restrict__ cur){
  int i = blockIdx.x*256 + threadIdx.x;
  if (i < N_NODES){
    int o = offs[i] + bsum[blockIdx.x];
    offs[i] = o; cur[i] = o;
  }
  if (i == 0) offs[N_NODES] = N_EDGES;
}

__global__ void k_scatter(const int* __restrict__ src, const int* __restrict__ dst,
                          int* __restrict__ cur, int* __restrict__ csr_src){
  int e = blockIdx.x*256 + threadIdx.x;
  if (e < N_EDGES){
    int pos = atomicAdd(&cur[dst[e]], 1);
    csr_src[pos] = src[e];
  }
}

// ---------------- per-edge attention weights, TRANSPOSED [4][E] (node-parallel) ------
// One wave per node (CSR walk -> no csr_dst needed). 64 lanes = 16 edges x 4 heads.
// evt[h][e] = exp(lrelu(el[src_e][h] + er[n][h])). All loads/stores coalesced or
// L2-resident (el = 800 KB). Removes the per-head phase-1 gather+exp from k_aggh.
__global__ __launch_bounds__(256) void k_edgev(const int* __restrict__ offs,
        const int* __restrict__ csr_src, const float* __restrict__ el,
        const float* __restrict__ er, float* __restrict__ evt){
  int tid  = threadIdx.x;
  int wv   = tid >> 6;
  int lane = tid & 63;
  int n    = blockIdx.x*4 + wv;       // 12500 * 4 = 50000 exactly
  int beg = offs[n], end = offs[n+1];
  int ej = lane & 15, hj = lane >> 4;
  float er_h = er[n*4 + hj];
  for (int cbeg = beg; cbeg < end; cbeg += 16){
    int e = cbeg + ej;
    if (e < end){
      int s = csr_src[e];
      evt[(size_t)hj*N_EDGES + e] = __expf(lrelu(el[s*4 + hj] + er_h));
    }
  }
}

// ---------------- MFMA GEMM: feat[N,HF] = h[N,128] @ W[128,HF] ----------------
// fp16 inputs, fp32 accumulate. Block tile 128x64, K=128 in LDS, XOR swizzle.
// C bounces through LDS for coalesced fp16 stores; el/er fused in readback.
template<int HF, bool AHALF>
__global__ __launch_bounds__(256) void k_gemm(const void* __restrict__ Ain,
        const _Float16* __restrict__ Wt,
        __half* __restrict__ feat,
        const float* __restrict__ al, const float* __restrict__ ar,
        float* __restrict__ el, float* __restrict__ er){
  __shared__ char lds[49152];
  char* Alds = lds;            // 128 x 128 halfs, swizzled (32 KB)
  char* Blds = lds + 32768;    // 64  x 128 halfs, swizzled (16 KB)
  _Float16* Clds = (_Float16*)lds;  // 128 x 80 halfs (20 KB), aliased over A
  const int tid  = threadIdx.x;
  const int row0 = blockIdx.x * 128;
  const int col0 = blockIdx.y * 64;

  if (AHALF){
    const __half* A16 = (const __half*)Ain;
    #pragma unroll
    for (int i = 0; i < 8; ++i){
      int flat = i*256 + tid;
      int r = flat >> 4, ch = flat & 15;
      uint4 v = make_uint4(0,0,0,0);
      if (row0 + r < N_NODES) v = *(const uint4*)&A16[(size_t)(row0+r)*128 + ch*8];
      *(uint4*)(Alds + ((r*256 + ch*16) ^ ((r&7)<<4))) = v;
    }
  } else {
    const float* A32 = (const float*)Ain;
    #pragma unroll
    for (int i = 0; i < 8; ++i){
      int flat = i*256 + tid;
      int r = flat >> 4, ch = flat & 15;
      h8 hv = {};
      if (row0 + r < N_NODES){
        float4 f0 = *(const float4*)&A32[(size_t)(row0+r)*128 + ch*8];
        float4 f1 = *(const float4*)&A32[(size_t)(row0+r)*128 + ch*8 + 4];
        hv[0]=(_Float16)f0.x; hv[1]=(_Float16)f0.y; hv[2]=(_Float16)f0.z; hv[3]=(_Float16)f0.w;
        hv[4]=(_Float16)f1.x; hv[5]=(_Float16)f1.y; hv[6]=(_Float16)f1.z; hv[7]=(_Float16)f1.w;
      }
      *(h8*)(Alds + ((r*256 + ch*16) ^ ((r&7)<<4))) = hv;
    }
  }
  #pragma unroll
  for (int i = 0; i < 4; ++i){
    int flat = i*256 + tid;
    int n = flat >> 4, ch = flat & 15;
    uint4 v = *(const uint4*)&Wt[(size_t)(col0+n)*128 + ch*8];
    *(uint4*)(Blds + ((n*256 + ch*16) ^ ((n&7)<<4))) = v;
  }
  __syncthreads();

  const int l = tid & 63, w = tid >> 6;
  f4 acc[2][4] = {};
  const int rA0  = w*32 + (l & 15);
  const int rA1  = rA0 + 16;
  const int nB   = (l & 15);
  const int ksel = (l >> 4) * 16;
  #pragma unroll
  for (int kb = 0; kb < 4; ++kb){
    int kofs = kb*64 + ksel;
    h8 a0 = *(const h8*)(Alds + ((rA0*256 + kofs) ^ ((rA0&7)<<4)));
    h8 a1 = *(const h8*)(Alds + ((rA1*256 + kofs) ^ ((rA1&7)<<4)));
    h8 b[4];
    #pragma unroll
    for (int nf = 0; nf < 4; ++nf){
      int n = nB + nf*16;
      b[nf] = *(const h8*)(Blds + ((n*256 + kofs) ^ ((n&7)<<4)));
    }
    #pragma unroll
    for (int nf = 0; nf < 4; ++nf){
      acc[0][nf] = __builtin_amdgcn_mfma_f32_16x16x32_f16(a0, b[nf], acc[0][nf], 0, 0, 0);
      acc[1][nf] = __builtin_amdgcn_mfma_f32_16x16x32_f16(a1, b[nf], acc[1][nf], 0, 0, 0);
    }
  }
  __syncthreads();

  #pragma unroll
  for (int mf = 0; mf < 2; ++mf){
    int rloc = w*32 + mf*16 + (l>>4)*4;
    #pragma unroll
    for (int nf = 0; nf < 4; ++nf){
      int c = nf*16 + (l&15);
      #pragma unroll
      for (int reg = 0; reg < 4; ++reg)
        Clds[(rloc+reg)*80 + c] = (_Float16)acc[mf][nf][reg];
    }
  }
  __syncthreads();

  constexpr int F = HF/4;
  int ch = l & 7;
  float4 al0 = *(const float4*)&al[col0 + ch*8];
  float4 al1 = *(const float4*)&al[col0 + ch*8 + 4];
  float4 ar0 = *(const float4*)&ar[col0 + ch*8];
  float4 ar1 = *(const float4*)&ar[col0 + ch*8 + 4];
  #pragma unroll
  for (int i = 0; i < 4; ++i){
    int rloc = i*32 + w*8 + (l>>3);
    int grow = row0 + rloc;
    h8 hv = *(const h8*)&Clds[rloc*80 + ch*8];
    if (grow < N_NODES)
      *(uint4*)&feat[(size_t)grow*HF + col0 + ch*8] = *(uint4*)&hv;
    float f0=(float)hv[0], f1=(float)hv[1], f2=(float)hv[2], f3=(float)hv[3];
    float f4_=(float)hv[4], f5=(float)hv[5], f6=(float)hv[6], f7=(float)hv[7];
    float pl = f0*al0.x + f1*al0.y + f2*al0.z + f3*al0.w
             + f4_*al1.x + f5*al1.y + f6*al1.z + f7*al1.w;
    float pr = f0*ar0.x + f1*ar0.y + f2*ar0.z + f3*ar0.w
             + f4_*ar1.x + f5*ar1.y + f6*ar1.z + f7*ar1.w;
    pl += __shfl_xor(pl, 1); pl += __shfl_xor(pl, 2);
    pr += __shfl_xor(pr, 1); pr += __shfl_xor(pr, 2);
    if (F == 64){ pl += __shfl_xor(pl, 4); pr += __shfl_xor(pr, 4); }
    bool lead = (F == 32) ? ((l & 3) == 0) : ((l & 7) == 0);
    if (lead && grow < N_NODES){
      int h = (col0 + ch*8) / F;
      el[grow*4 + h] = pl;
      er[grow*4 + h] = pr;
    }
  }
}

// ---------------- F=32 aggregation, per-head cache-blocked, precomputed ev ----------
// head = blockIdx.y (x fastest -> heads temporally separated; 3.2 MB slice fits
// per-XCD L2 -> gathers are L2 hits; R7 proved FETCH drops to the ~137 MB fill
// floor). Phase 1 is now just TWO COALESCED loads (csr_src, evt[h]) -- the 4x
// gather+exp that made R7 slow is gone (precomputed by k_edgev).
template<int LAYER>
__global__ __launch_bounds__(256) void k_aggh(const int* __restrict__ offs,
        const int* __restrict__ csr_src, const float* __restrict__ evt,
        const __half* __restrict__ feat,
        const float* __restrict__ bias, __half* __restrict__ out){
  __shared__ float s_ev[4][64];
  __shared__ int   s_src[4][64];
  int tid  = threadIdx.x;
  int wv   = tid >> 6;
  int lane = tid & 63;
  int h    = blockIdx.y;
  int n    = blockIdx.x*4 + wv;      // 12500 x-blocks * 4 waves = 50000 exactly
  int beg = offs[n], end = offs[n+1];
  const float* evh = evt + (size_t)h*N_EDGES;
  int eg = lane >> 2;                // edge group 0..15
  int fq = lane & 3;                 // 16B slot within the 64B head slice
  float a0=0.f,a1=0.f,a2=0.f,a3=0.f,a4=0.f,a5=0.f,a6=0.f,a7=0.f,ds=0.f;

  for (int cbeg = beg; cbeg < end; cbeg += 64){
    int m = end - cbeg; if (m > 64) m = 64;
    // ---- phase 1: two coalesced loads into LDS (no gather, no exp) ----
    if (lane < m){
      s_src[wv][lane] = csr_src[cbeg + lane];
      s_ev[wv][lane]  = evh[cbeg + lane];
    }
    asm volatile("s_waitcnt lgkmcnt(0)" ::: "memory");
    // ---- phase 2: 16 edges / iteration, one 64B L2-hit line per edge ----
    #pragma unroll 2
    for (int i = 0; i < m; i += 16){
      int e = i + eg;
      if (e < m){
        int s = s_src[wv][e];
        float w = s_ev[wv][e];
        ds += w;
        uint4 raw = *(const uint4*)&feat[(size_t)s*128 + h*32 + fq*8];
        const __half2* hp = reinterpret_cast<const __half2*>(&raw);
        float2 f0 = __half22float2(hp[0]);
        float2 f1 = __half22float2(hp[1]);
        float2 f2 = __half22float2(hp[2]);
        float2 f3 = __half22float2(hp[3]);
        a0 += w*f0.x; a1 += w*f0.y; a2 += w*f1.x; a3 += w*f1.y;
        a4 += w*f2.x; a5 += w*f2.y; a6 += w*f3.x; a7 += w*f3.y;
      }
    }
    asm volatile("" ::: "memory");   // keep next chunk's LDS writes behind these reads
  }
  // ---- reduce over the 16 edge groups (stride-4 lanes share features) ----
  #pragma unroll
  for (int msk = 4; msk < 64; msk <<= 1){
    ds += __shfl_xor(ds, msk);
    a0 += __shfl_xor(a0, msk); a1 += __shfl_xor(a1, msk);
    a2 += __shfl_xor(a2, msk); a3 += __shfl_xor(a3, msk);
    a4 += __shfl_xor(a4, msk); a5 += __shfl_xor(a5, msk);
    a6 += __shfl_xor(a6, msk); a7 += __shfl_xor(a7, msk);
  }
  if (eg == 0){
    float rden = 1.f / fmaxf(ds, 1e-9f);
    float4 b0 = *(const float4*)&bias[h*32 + fq*8];
    float4 b1 = *(const float4*)&bias[h*32 + fq*8 + 4];
    float o0 = eluf(a0*rden + b0.x);
    float o1 = eluf(a1*rden + b0.y);
    float o2 = eluf(a2*rden + b0.z);
    float o3 = eluf(a3*rden + b0.w);
    float o4 = eluf(a4*rden + b1.x);
    float o5 = eluf(a5*rden + b1.y);
    float o6 = eluf(a6*rden + b1.z);
    float o7 = eluf(a7*rden + b1.w);
    h8 hv;
    hv[0]=(_Float16)o0; hv[1]=(_Float16)o1; hv[2]=(_Float16)o2; hv[3]=(_Float16)o3;
    hv[4]=(_Float16)o4; hv[5]=(_Float16)o5; hv[6]=(_Float16)o6; hv[7]=(_Float16)o7;
    *(uint4*)&out[(size_t)n*128 + h*32 + fq*8] = *(uint4*)&hv;
  }
}

// ---------------- F=64 final layer: fused softmax + aggregation + head-mean ----------
// (R6 structure; per-head slice would be 6.4 MB > per-XCD L2, no blocking win)
template<int F, bool FINAL, int LAYER>
__global__ __launch_bounds__(256) void k_agg(const int* __restrict__ offs,
        const int* __restrict__ csr_src, const float* __restrict__ el,
        const float* __restrict__ er, const __half* __restrict__ feat,
        const float* __restrict__ bias, void* __restrict__ out){
  __shared__ float s_ev[4][64][4];   // [wave][edge][head]
  __shared__ int   s_src[4][64];     // [wave][edge]
  int tid  = threadIdx.x;
  int wv   = tid >> 6;
  int lane = tid & 63;
  int n = blockIdx.x*4 + wv;
  int beg = offs[n], end = offs[n+1];
  float4 er4 = ((const float4*)er)[n];

  int hw  = lane >> 5;
  int l5  = lane & 31;
  int h   = l5 >> 3;
  float a0=0.f,a1=0.f,a2=0.f,a3=0.f,a4=0.f,a5=0.f,a6=0.f,a7=0.f,ds=0.f;
  for (int cbeg = beg; cbeg < end; cbeg += 64){
    int m = end - cbeg; if (m > 64) m = 64;
    if (lane < m){
      int s = csr_src[cbeg + lane];
      s_src[wv][lane] = s;
      float4 e4 = *(const float4*)&el[(size_t)s*4];
      float4 ev4;
      ev4.x = __expf(lrelu(e4.x + er4.x));
      ev4.y = __expf(lrelu(e4.y + er4.y));
      ev4.z = __expf(lrelu(e4.z + er4.z));
      ev4.w = __expf(lrelu(e4.w + er4.w));
      *(float4*)&s_ev[wv][lane][0] = ev4;
    }
    asm volatile("s_waitcnt lgkmcnt(0)" ::: "memory");
    #pragma unroll 4
    for (int i = 0; i < m; i += 2){
      int e = i + hw;
      if (e < m){
        int s = s_src[wv][e];
        float w = s_ev[wv][e][h];
        ds += w;
        uint4 raw = *(const uint4*)&feat[(size_t)s*256 + l5*8];
        const __half2* hp = reinterpret_cast<const __half2*>(&raw);
        float2 f0 = __half22float2(hp[0]);
        float2 f1 = __half22float2(hp[1]);
        float2 f2 = __half22float2(hp[2]);
        float2 f3 = __half22float2(hp[3]);
        a0 += w*f0.x; a1 += w*f0.y; a2 += w*f1.x; a3 += w*f1.y;
        a4 += w*f2.x; a5 += w*f2.y; a6 += w*f3.x; a7 += w*f3.y;
      }
    }
    asm volatile("" ::: "memory");
  }
  ds += __shfl_xor(ds, 32);
  a0 += __shfl_xor(a0, 32); a1 += __shfl_xor(a1, 32);
  a2 += __shfl_xor(a2, 32); a3 += __shfl_xor(a3, 32);
  a4 += __shfl_xor(a4, 32); a5 += __shfl_xor(a5, 32);
  a6 += __shfl_xor(a6, 32); a7 += __shfl_xor(a7, 32);
  float rden = 1.f / fmaxf(ds, 1e-9f);
  float4 b0 = *(const float4*)&bias[l5*8];
  float4 b1 = *(const float4*)&bias[l5*8 + 4];
  float v0 = a0*rden + b0.x;
  float v1 = a1*rden + b0.y;
  float v2 = a2*rden + b0.z;
  float v3 = a3*rden + b0.w;
  float v4 = a4*rden + b1.x;
  float v5 = a5*rden + b1.y;
  float v6 = a6*rden + b1.z;
  float v7 = a7*rden + b1.w;
  v0 += __shfl_xor(v0, 8); v0 += __shfl_xor(v0, 16);
  v1 += __shfl_xor(v1, 8); v1 += __shfl_xor(v1, 16);
  v2 += __shfl_xor(v2, 8); v2 += __shfl_xor(v2, 16);
  v3 += __shfl_xor(v3, 8); v3 += __shfl_xor(v3, 16);
  v4 += __shfl_xor(v4, 8); v4 += __shfl_xor(v4, 16);
  v5 += __shfl_xor(v5, 8); v5 += __shfl_xor(v5, 16);
  v6 += __shfl_xor(v6, 8); v6 += __shfl_xor(v6, 16);
  v7 += __shfl_xor(v7, 8); v7 += __shfl_xor(v7, 16);
  if (hw == 0 && l5 < 8){
    float* outf = (float*)out;       // final layer: fp32
    *(float4*)&outf[(size_t)n*64 + l5*8] =
      make_float4(v0*0.25f, v1*0.25f, v2*0.25f, v3*0.25f);
    *(float4*)&outf[(size_t)n*64 + l5*8 + 4] =
      make_float4(v4*0.25f, v5*0.25f, v6*0.25f, v7*0.25f);
  }
}

extern "C" void kernel_launch(void* const* d_in, const int* in_sizes, int n_in,
                              void* d_out, int out_size, void* d_ws, size_t ws_size,
                              hipStream_t stream){
  const float* x   = (const float*)d_in[0];
  const int*   src = (const int*)  d_in[1];
  const int*   dst = (const int*)  d_in[2];
  const float* W[4]  = {(const float*)d_in[3],  (const float*)d_in[7],
                        (const float*)d_in[11], (const float*)d_in[15]};
  const float* al[4] = {(const float*)d_in[4],  (const float*)d_in[8],
                        (const float*)d_in[12], (const float*)d_in[16]};
  const float* ar[4] = {(const float*)d_in[5],  (const float*)d_in[9],
                        (const float*)d_in[13], (const float*)d_in[17]};
  const float* b[4]  = {(const float*)d_in[6],  (const float*)d_in[10],
                        (const float*)d_in[14], (const float*)d_in[18]};

  char* ws = (char*)d_ws;
  __half*    bufH    = (__half*)   (ws);             // fp16 (12.8 MB used)
  __half*    feat    = (__half*)   (ws + 25600000);  // 25.6 MB
  _Float16*  wt      = (_Float16*) (ws + 51200000);  // 163,840 B
  float*     evt     = (float*)    (ws + 60000000);  // 12.8 MB transposed ev [4][E]
  float*     el      = (float*)    (ws + 76800000);  // 800,000
  float*     er      = (float*)    (ws + 77600000);  // 800,000
  int*       offs    = (int*)      (ws + 78400000);  // 200,004 (padded)
  int*       cur     = (int*)      (ws + 78600032);  // 200,000
  int*       bsum    = (int*)      (ws + 78800032);  // 1,024
  int*       csr_src = (int*)      (ws + 78801056);  // 3,200,000 (end ~82 MB)

  // ---- CSR build + fused weight transpose ----
  (void)hipMemsetAsync(cur, 0, N_NODES*sizeof(int), stream);
  k_histwt <<<3445, 256, 0, stream>>>(dst, cur, W[0], W[1], W[2], W[3], wt);
  k_scan1  <<<196,  256, 0, stream>>>(cur, offs, bsum);
  k_scan2  <<<1,    256, 0, stream>>>(bsum, 196);
  k_scan3  <<<196,  256, 0, stream>>>(offs, bsum, cur);
  k_scatter<<<3125, 256, 0, stream>>>(src, dst, cur, csr_src);

  // ---- layer 1..3 (HF=128, F=32): per-head cache-blocked aggregation ----
  k_gemm<128,false><<<dim3(391,2), 256, 0, stream>>>(x, wt, feat, al[0], ar[0], el, er);
  k_edgev<<<12500, 256, 0, stream>>>(offs, csr_src, el, er, evt);
  k_aggh<1><<<dim3(12500,4), 256, 0, stream>>>(offs, csr_src, evt, feat, b[0], bufH);

  k_gemm<128,true><<<dim3(391,2), 256, 0, stream>>>(bufH, wt + 16384, feat, al[1], ar[1], el, er);
  k_edgev<<<12500, 256, 0, stream>>>(offs, csr_src, el, er, evt);
  k_aggh<2><<<dim3(12500,4), 256, 0, stream>>>(offs, csr_src, evt, feat, b[1], bufH);

  k_gemm<128,true><<<dim3(391,2), 256, 0, stream>>>(bufH, wt + 32768, feat, al[2], ar[2], el, er);
  k_edgev<<<12500, 256, 0, stream>>>(offs, csr_src, el, er, evt);
  k_aggh<3><<<dim3(12500,4), 256, 0, stream>>>(offs, csr_src, evt, feat, b[2], bufH);

  // ---- layer 4 (HF=256, F=64) + head-mean ----
  k_gemm<256,true><<<dim3(391,4), 256, 0, stream>>>(bufH, wt + 49152, feat, al[3], ar[3], el, er);
  k_agg<64,true,4><<<12500, 256, 0, stream>>>(offs, csr_src, el, er, feat, b[3], d_out);
}

// Round 9
// 393.213 us; speedup vs baseline: 1.5855x; 1.5855x over previous
//
#include <hip/hip_runtime.h>
#include <hip/hip_fp16.h>

#define N_NODES 50000
#define N_EDGES 800000

typedef _Float16 h8 __attribute__((ext_vector_type(8)));
typedef float f4 __attribute__((ext_vector_type(4)));

__device__ __forceinline__ float lrelu(float x){ return x > 0.f ? x : 0.2f*x; }
__device__ __forceinline__ float eluf (float x){ return x > 0.f ? x : __expf(x)-1.f; }

// ---------------- CSR build (+ fused weight transpose) ----------------
// Histogram also records each edge's arrival rank within its dst bucket, so the
// scatter pass needs NO atomic (plain fire-and-forget store instead of RMW).
__global__ void k_histwt(const int* __restrict__ dst, int* __restrict__ cnt,
                         int* __restrict__ rank,
                         const float* __restrict__ W1, const float* __restrict__ W2,
                         const float* __restrict__ W3, const float* __restrict__ W4,
                         _Float16* __restrict__ wt){
  int b = blockIdx.x;
  if (b < 3125){
    int e = b*256 + threadIdx.x;
    if (e < N_EDGES) rank[e] = atomicAdd(&cnt[dst[e]], 1);
  } else {
    int id = (b - 3125)*256 + threadIdx.x;     // 81920 total wt elements
    if (id < 81920){
      const float* W; int HF; int loc;
      if (id < 16384)      { W = W1; HF = 128; loc = id; }
      else if (id < 32768) { W = W2; HF = 128; loc = id - 16384; }
      else if (id < 49152) { W = W3; HF = 128; loc = id - 32768; }
      else                 { W = W4; HF = 256; loc = id - 49152; }
      int n = loc >> 7, k = loc & 127;
      wt[id] = (_Float16)W[(size_t)k*HF + n];
    }
  }
}

__global__ void k_scan1(const int* __restrict__ cnt, int* __restrict__ offs, int* __restrict__ bsum){
  __shared__ int tmp[256];
  int tid = threadIdx.x; int i = blockIdx.x*256 + tid;
  int v = (i < N_NODES) ? cnt[i] : 0;
  tmp[tid] = v; __syncthreads();
  for (int d = 1; d < 256; d <<= 1){
    int t = (tid >= d) ? tmp[tid-d] : 0;
    __syncthreads();
    tmp[tid] += t;
    __syncthreads();
  }
  if (i < N_NODES) offs[i] = tmp[tid] - v;
  if (tid == 255) bsum[blockIdx.x] = tmp[tid];
}

__global__ void k_scan2(int* __restrict__ bsum, int nb){
  __shared__ int tmp[256];
  int tid = threadIdx.x;
  int v = (tid < nb) ? bsum[tid] : 0;
  tmp[tid] = v; __syncthreads();
  for (int d = 1; d < 256; d <<= 1){
    int t = (tid >= d) ? tmp[tid-d] : 0;
    __syncthreads();
    tmp[tid] += t;
    __syncthreads();
  }
  if (tid < nb) bsum[tid] = tmp[tid] - v;
}

__global__ void k_scan3(int* __restrict__ offs, const int* __restrict__ bsum){
  int i = blockIdx.x*256 + threadIdx.x;
  if (i < N_NODES) offs[i] += bsum[blockIdx.x];
  if (i == 0) offs[N_NODES] = N_EDGES;
}

__global__ void k_scatter(const int* __restrict__ src, const int* __restrict__ dst,
                          const int* __restrict__ offs, const int* __restrict__ rank,
                          int* __restrict__ csr_src){
  int e = blockIdx.x*256 + threadIdx.x;
  if (e < N_EDGES){
    csr_src[offs[dst[e]] + rank[e]] = src[e];   // no atomic: rank precomputed
  }
}

// ---------------- MFMA GEMM: feat[N,HF] = h[N,128] @ W[128,HF] ----------------
// fp16 inputs, fp32 accumulate. Block tile 128x64, K=128 in LDS, XOR swizzle.
// C bounces through LDS for coalesced fp16 stores; el/er fused in readback.
template<int HF, bool AHALF>
__global__ __launch_bounds__(256) void k_gemm(const void* __restrict__ Ain,
        const _Float16* __restrict__ Wt,
        __half* __restrict__ feat,
        const float* __restrict__ al, const float* __restrict__ ar,
        float* __restrict__ el, float* __restrict__ er){
  __shared__ char lds[49152];
  char* Alds = lds;            // 128 x 128 halfs, swizzled (32 KB)
  char* Blds = lds + 32768;    // 64  x 128 halfs, swizzled (16 KB)
  _Float16* Clds = (_Float16*)lds;  // 128 x 80 halfs (20 KB), aliased over A
  const int tid  = threadIdx.x;
  const int row0 = blockIdx.x * 128;
  const int col0 = blockIdx.y * 64;

  if (AHALF){
    const __half* A16 = (const __half*)Ain;
    #pragma unroll
    for (int i = 0; i < 8; ++i){
      int flat = i*256 + tid;
      int r = flat >> 4, ch = flat & 15;
      uint4 v = make_uint4(0,0,0,0);
      if (row0 + r < N_NODES) v = *(const uint4*)&A16[(size_t)(row0+r)*128 + ch*8];
      *(uint4*)(Alds + ((r*256 + ch*16) ^ ((r&7)<<4))) = v;
    }
  } else {
    const float* A32 = (const float*)Ain;
    #pragma unroll
    for (int i = 0; i < 8; ++i){
      int flat = i*256 + tid;
      int r = flat >> 4, ch = flat & 15;
      h8 hv = {};
      if (row0 + r < N_NODES){
        float4 f0 = *(const float4*)&A32[(size_t)(row0+r)*128 + ch*8];
        float4 f1 = *(const float4*)&A32[(size_t)(row0+r)*128 + ch*8 + 4];
        hv[0]=(_Float16)f0.x; hv[1]=(_Float16)f0.y; hv[2]=(_Float16)f0.z; hv[3]=(_Float16)f0.w;
        hv[4]=(_Float16)f1.x; hv[5]=(_Float16)f1.y; hv[6]=(_Float16)f1.z; hv[7]=(_Float16)f1.w;
      }
      *(h8*)(Alds + ((r*256 + ch*16) ^ ((r&7)<<4))) = hv;
    }
  }
  #pragma unroll
  for (int i = 0; i < 4; ++i){
    int flat = i*256 + tid;
    int n = flat >> 4, ch = flat & 15;
    uint4 v = *(const uint4*)&Wt[(size_t)(col0+n)*128 + ch*8];
    *(uint4*)(Blds + ((n*256 + ch*16) ^ ((n&7)<<4))) = v;
  }
  __syncthreads();

  const int l = tid & 63, w = tid >> 6;
  f4 acc[2][4] = {};
  const int rA0  = w*32 + (l & 15);
  const int rA1  = rA0 + 16;
  const int nB   = (l & 15);
  const int ksel = (l >> 4) * 16;
  #pragma unroll
  for (int kb = 0; kb < 4; ++kb){
    int kofs = kb*64 + ksel;
    h8 a0 = *(const h8*)(Alds + ((rA0*256 + kofs) ^ ((rA0&7)<<4)));
    h8 a1 = *(const h8*)(Alds + ((rA1*256 + kofs) ^ ((rA1&7)<<4)));
    h8 b[4];
    #pragma unroll
    for (int nf = 0; nf < 4; ++nf){
      int n = nB + nf*16;
      b[nf] = *(const h8*)(Blds + ((n*256 + kofs) ^ ((n&7)<<4)));
    }
    #pragma unroll
    for (int nf = 0; nf < 4; ++nf){
      acc[0][nf] = __builtin_amdgcn_mfma_f32_16x16x32_f16(a0, b[nf], acc[0][nf], 0, 0, 0);
      acc[1][nf] = __builtin_amdgcn_mfma_f32_16x16x32_f16(a1, b[nf], acc[1][nf], 0, 0, 0);
    }
  }
  __syncthreads();

  #pragma unroll
  for (int mf = 0; mf < 2; ++mf){
    int rloc = w*32 + mf*16 + (l>>4)*4;
    #pragma unroll
    for (int nf = 0; nf < 4; ++nf){
      int c = nf*16 + (l&15);
      #pragma unroll
      for (int reg = 0; reg < 4; ++reg)
        Clds[(rloc+reg)*80 + c] = (_Float16)acc[mf][nf][reg];
    }
  }
  __syncthreads();

  constexpr int F = HF/4;
  int ch = l & 7;
  float4 al0 = *(const float4*)&al[col0 + ch*8];
  float4 al1 = *(const float4*)&al[col0 + ch*8 + 4];
  float4 ar0 = *(const float4*)&ar[col0 + ch*8];
  float4 ar1 = *(const float4*)&ar[col0 + ch*8 + 4];
  #pragma unroll
  for (int i = 0; i < 4; ++i){
    int rloc = i*32 + w*8 + (l>>3);
    int grow = row0 + rloc;
    h8 hv = *(const h8*)&Clds[rloc*80 + ch*8];
    if (grow < N_NODES)
      *(uint4*)&feat[(size_t)grow*HF + col0 + ch*8] = *(uint4*)&hv;
    float f0=(float)hv[0], f1=(float)hv[1], f2=(float)hv[2], f3=(float)hv[3];
    float f4_=(float)hv[4], f5=(float)hv[5], f6=(float)hv[6], f7=(float)hv[7];
    float pl = f0*al0.x + f1*al0.y + f2*al0.z + f3*al0.w
             + f4_*al1.x + f5*al1.y + f6*al1.z + f7*al1.w;
    float pr = f0*ar0.x + f1*ar0.y + f2*ar0.z + f3*ar0.w
             + f4_*ar1.x + f5*ar1.y + f6*ar1.z + f7*ar1.w;
    pl += __shfl_xor(pl, 1); pl += __shfl_xor(pl, 2);
    pr += __shfl_xor(pr, 1); pr += __shfl_xor(pr, 2);
    if (F == 64){ pl += __shfl_xor(pl, 4); pr += __shfl_xor(pr, 4); }
    bool lead = (F == 32) ? ((l & 3) == 0) : ((l & 7) == 0);
    if (lead && grow < N_NODES){
      int h = (col0 + ch*8) / F;
      el[grow*4 + h] = pl;
      er[grow*4 + h] = pr;
    }
  }
}

// ---------------- F=32 fused softmax + aggregation (1 wave / node) ----------------
// R3/R6 structure — best measured. Two-phase per 64-edge chunk, LDS-staged
// {src, ev4}. Phase 2: 4 edges/iter, one 256B run per edge (~13M runs/s law).
template<int LAYER>
__global__ __launch_bounds__(256) void k_agg(const int* __restrict__ offs,
        const int* __restrict__ csr_src, const float* __restrict__ el,
        const float* __restrict__ er, const __half* __restrict__ feat,
        const float* __restrict__ bias, __half* __restrict__ out){
  __shared__ float s_ev[4][64][4];   // [wave][edge][head]
  __shared__ int   s_src[4][64];     // [wave][edge]
  int tid  = threadIdx.x;
  int wv   = tid >> 6;
  int lane = tid & 63;
  int n = blockIdx.x*4 + wv;         // 12500 blocks * 4 waves = 50000 exactly
  int beg = offs[n], end = offs[n+1];
  float4 er4 = ((const float4*)er)[n];

  int quarter = lane >> 4;
  int l4      = lane & 15;
  int h       = l4 >> 2;
  float a0=0.f,a1=0.f,a2=0.f,a3=0.f,a4=0.f,a5=0.f,a6=0.f,a7=0.f,ds=0.f;
  for (int cbeg = beg; cbeg < end; cbeg += 64){
    int m = end - cbeg; if (m > 64) m = 64;
    if (lane < m){
      int s = csr_src[cbeg + lane];
      s_src[wv][lane] = s;
      float4 e4 = *(const float4*)&el[(size_t)s*4];
      float4 ev4;
      ev4.x = __expf(lrelu(e4.x + er4.x));
      ev4.y = __expf(lrelu(e4.y + er4.y));
      ev4.z = __expf(lrelu(e4.z + er4.z));
      ev4.w = __expf(lrelu(e4.w + er4.w));
      *(float4*)&s_ev[wv][lane][0] = ev4;
    }
    asm volatile("s_waitcnt lgkmcnt(0)" ::: "memory");
    #pragma unroll 4
    for (int i = 0; i < m; i += 4){
      int e = i + quarter;
      if (e < m){
        int s = s_src[wv][e];
        float w = s_ev[wv][e][h];
        ds += w;
        uint4 raw = *(const uint4*)&feat[(size_t)s*128 + l4*8];
        const __half2* hp = reinterpret_cast<const __half2*>(&raw);
        float2 f0 = __half22float2(hp[0]);
        float2 f1 = __half22float2(hp[1]);
        float2 f2 = __half22float2(hp[2]);
        float2 f3 = __half22float2(hp[3]);
        a0 += w*f0.x; a1 += w*f0.y; a2 += w*f1.x; a3 += w*f1.y;
        a4 += w*f2.x; a5 += w*f2.y; a6 += w*f3.x; a7 += w*f3.y;
      }
    }
    asm volatile("" ::: "memory");   // keep next chunk's LDS writes behind these reads
  }
  ds += __shfl_xor(ds, 16); ds += __shfl_xor(ds, 32);
  a0 += __shfl_xor(a0, 16); a0 += __shfl_xor(a0, 32);
  a1 += __shfl_xor(a1, 16); a1 += __shfl_xor(a1, 32);
  a2 += __shfl_xor(a2, 16); a2 += __shfl_xor(a2, 32);
  a3 += __shfl_xor(a3, 16); a3 += __shfl_xor(a3, 32);
  a4 += __shfl_xor(a4, 16); a4 += __shfl_xor(a4, 32);
  a5 += __shfl_xor(a5, 16); a5 += __shfl_xor(a5, 32);
  a6 += __shfl_xor(a6, 16); a6 += __shfl_xor(a6, 32);
  a7 += __shfl_xor(a7, 16); a7 += __shfl_xor(a7, 32);
  if (quarter == 0){
    float rden = 1.f / fmaxf(ds, 1e-9f);
    float4 b0 = *(const float4*)&bias[l4*8];
    float4 b1 = *(const float4*)&bias[l4*8 + 4];
    float o0 = eluf(a0*rden + b0.x);
    float o1 = eluf(a1*rden + b0.y);
    float o2 = eluf(a2*rden + b0.z);
    float o3 = eluf(a3*rden + b0.w);
    float o4 = eluf(a4*rden + b1.x);
    float o5 = eluf(a5*rden + b1.y);
    float o6 = eluf(a6*rden + b1.z);
    float o7 = eluf(a7*rden + b1.w);
    h8 hv;
    hv[0]=(_Float16)o0; hv[1]=(_Float16)o1; hv[2]=(_Float16)o2; hv[3]=(_Float16)o3;
    hv[4]=(_Float16)o4; hv[5]=(_Float16)o5; hv[6]=(_Float16)o6; hv[7]=(_Float16)o7;
    *(uint4*)&out[(size_t)n*128 + l4*8] = *(uint4*)&hv;
  }
}

// ---------------- F=64 final layer (distinct name for counter visibility) ----------
__global__ __launch_bounds__(256) void k_agg64(const int* __restrict__ offs,
        const int* __restrict__ csr_src, const float* __restrict__ el,
        const float* __restrict__ er, const __half* __restrict__ feat,
        const float* __restrict__ bias, float* __restrict__ out){
  __shared__ float s_ev[4][64][4];   // [wave][edge][head]
  __shared__ int   s_src[4][64];     // [wave][edge]
  int tid  = threadIdx.x;
  int wv   = tid >> 6;
  int lane = tid & 63;
  int n = blockIdx.x*4 + wv;
  int beg = offs[n], end = offs[n+1];
  float4 er4 = ((const float4*)er)[n];

  int hw  = lane >> 5;
  int l5  = lane & 31;
  int h   = l5 >> 3;
  float a0=0.f,a1=0.f,a2=0.f,a3=0.f,a4=0.f,a5=0.f,a6=0.f,a7=0.f,ds=0.f;
  for (int cbeg = beg; cbeg < end; cbeg += 64){
    int m = end - cbeg; if (m > 64) m = 64;
    if (lane < m){
      int s = csr_src[cbeg + lane];
      s_src[wv][lane] = s;
      float4 e4 = *(const float4*)&el[(size_t)s*4];
      float4 ev4;
      ev4.x = __expf(lrelu(e4.x + er4.x));
      ev4.y = __expf(lrelu(e4.y + er4.y));
      ev4.z = __expf(lrelu(e4.z + er4.z));
      ev4.w = __expf(lrelu(e4.w + er4.w));
      *(float4*)&s_ev[wv][lane][0] = ev4;
    }
    asm volatile("s_waitcnt lgkmcnt(0)" ::: "memory");
    #pragma unroll 4
    for (int i = 0; i < m; i += 2){
      int e = i + hw;
      if (e < m){
        int s = s_src[wv][e];
        float w = s_ev[wv][e][h];
        ds += w;
        uint4 raw = *(const uint4*)&feat[(size_t)s*256 + l5*8];
        const __half2* hp = reinterpret_cast<const __half2*>(&raw);
        float2 f0 = __half22float2(hp[0]);
        float2 f1 = __half22float2(hp[1]);
        float2 f2 = __half22float2(hp[2]);
        float2 f3 = __half22float2(hp[3]);
        a0 += w*f0.x; a1 += w*f0.y; a2 += w*f1.x; a3 += w*f1.y;
        a4 += w*f2.x; a5 += w*f2.y; a6 += w*f3.x; a7 += w*f3.y;
      }
    }
    asm volatile("" ::: "memory");
  }
  ds += __shfl_xor(ds, 32);
  a0 += __shfl_xor(a0, 32); a1 += __shfl_xor(a1, 32);
  a2 += __shfl_xor(a2, 32); a3 += __shfl_xor(a3, 32);
  a4 += __shfl_xor(a4, 32); a5 += __shfl_xor(a5, 32);
  a6 += __shfl_xor(a6, 32); a7 += __shfl_xor(a7, 32);
  float rden = 1.f / fmaxf(ds, 1e-9f);
  float4 b0 = *(const float4*)&bias[l5*8];
  float4 b1 = *(const float4*)&bias[l5*8 + 4];
  float v0 = a0*rden + b0.x;
  float v1 = a1*rden + b0.y;
  float v2 = a2*rden + b0.z;
  float v3 = a3*rden + b0.w;
  float v4 = a4*rden + b1.x;
  float v5 = a5*rden + b1.y;
  float v6 = a6*rden + b1.z;
  float v7 = a7*rden + b1.w;
  v0 += __shfl_xor(v0, 8); v0 += __shfl_xor(v0, 16);
  v1 += __shfl_xor(v1, 8); v1 += __shfl_xor(v1, 16);
  v2 += __shfl_xor(v2, 8); v2 += __shfl_xor(v2, 16);
  v3 += __shfl_xor(v3, 8); v3 += __shfl_xor(v3, 16);
  v4 += __shfl_xor(v4, 8); v4 += __shfl_xor(v4, 16);
  v5 += __shfl_xor(v5, 8); v5 += __shfl_xor(v5, 16);
  v6 += __shfl_xor(v6, 8); v6 += __shfl_xor(v6, 16);
  v7 += __shfl_xor(v7, 8); v7 += __shfl_xor(v7, 16);
  if (hw == 0 && l5 < 8){
    *(float4*)&out[(size_t)n*64 + l5*8] =
      make_float4(v0*0.25f, v1*0.25f, v2*0.25f, v3*0.25f);
    *(float4*)&out[(size_t)n*64 + l5*8 + 4] =
      make_float4(v4*0.25f, v5*0.25f, v6*0.25f, v7*0.25f);
  }
}

extern "C" void kernel_launch(void* const* d_in, const int* in_sizes, int n_in,
                              void* d_out, int out_size, void* d_ws, size_t ws_size,
                              hipStream_t stream){
  const float* x   = (const float*)d_in[0];
  const int*   src = (const int*)  d_in[1];
  const int*   dst = (const int*)  d_in[2];
  const float* W[4]  = {(const float*)d_in[3],  (const float*)d_in[7],
                        (const float*)d_in[11], (const float*)d_in[15]};
  const float* al[4] = {(const float*)d_in[4],  (const float*)d_in[8],
                        (const float*)d_in[12], (const float*)d_in[16]};
  const float* ar[4] = {(const float*)d_in[5],  (const float*)d_in[9],
                        (const float*)d_in[13], (const float*)d_in[17]};
  const float* b[4]  = {(const float*)d_in[6],  (const float*)d_in[10],
                        (const float*)d_in[14], (const float*)d_in[18]};

  char* ws = (char*)d_ws;
  __half*    bufH    = (__half*)   (ws);             // fp16 (12.8 MB used)
  __half*    feat    = (__half*)   (ws + 25600000);  // 25.6 MB
  _Float16*  wt      = (_Float16*) (ws + 51200000);  // 163,840 B
  int*       rank    = (int*)      (ws + 60000000);  // 3.2 MB (edge rank in bucket)
  float*     el      = (float*)    (ws + 76800000);  // 800,000
  float*     er      = (float*)    (ws + 77600000);  // 800,000
  int*       offs    = (int*)      (ws + 78400000);  // 200,004 (padded)
  int*       cnt     = (int*)      (ws + 78600032);  // 200,000
  int*       bsum    = (int*)      (ws + 78800032);  // 1,024
  int*       csr_src = (int*)      (ws + 78801056);  // 3,200,000 (end ~82 MB)

  // ---- CSR build (rank-based, atomic-free scatter) + fused weight transpose ----
  (void)hipMemsetAsync(cnt, 0, N_NODES*sizeof(int), stream);
  k_histwt <<<3445, 256, 0, stream>>>(dst, cnt, rank, W[0], W[1], W[2], W[3], wt);
  k_scan1  <<<196,  256, 0, stream>>>(cnt, offs, bsum);
  k_scan2  <<<1,    256, 0, stream>>>(bsum, 196);
  k_scan3  <<<196,  256, 0, stream>>>(offs, bsum);
  k_scatter<<<3125, 256, 0, stream>>>(src, dst, offs, rank, csr_src);

  // ---- layer 1..3 (HF=128, F=32) ----
  k_gemm<128,false><<<dim3(391,2), 256, 0, stream>>>(x, wt, feat, al[0], ar[0], el, er);
  k_agg<1><<<12500, 256, 0, stream>>>(offs, csr_src, el, er, feat, b[0], bufH);

  k_gemm<128,true><<<dim3(391,2), 256, 0, stream>>>(bufH, wt + 16384, feat, al[1], ar[1], el, er);
  k_agg<2><<<12500, 256, 0, stream>>>(offs, csr_src, el, er, feat, b[1], bufH);

  k_gemm<128,true><<<dim3(391,2), 256, 0, stream>>>(bufH, wt + 32768, feat, al[2], ar[2], el, er);
  k_agg<3><<<12500, 256, 0, stream>>>(offs, csr_src, el, er, feat, b[2], bufH);

  // ---- layer 4 (HF=256, F=64) + head-mean ----
  k_gemm<256,true><<<dim3(391,4), 256, 0, stream>>>(bufH, wt + 49152, feat, al[3], ar[3], el, er);
  k_agg64<<<12500, 256, 0, stream>>>(offs, csr_src, el, er, feat, b[3], (float*)d_out);
}